// Round 2
// baseline (234.922 us; speedup 1.0000x reference)
//
#include <hip/hip_runtime.h>

// Adder2D: out[n,h,w,f] = bias[f] - sum_{i,j,c} |x[n,h+i-1,w+j-1,c] - K[i,j,c,f]|
// x: [32,32,32,128] f32, K: [3,3,128,128] f32, bias: [128] f32, out: [32,32,32,128] f32.
// VALU-bound (no MFMA possible: |x-w| is not bilinear). Strategy: packed f16 pairs
// over the channel dim:
//   v_pk_add_f16 (diff) + v_and_b32 (packed abs) + v_dot2_f32_f16 (f32 accumulate)
// = 1.5 VALU instr per element-op vs 2.0 for scalar f32.

typedef _Float16 v2h  __attribute__((ext_vector_type(2)));   // arithmetic type
typedef __fp16   v2hb __attribute__((ext_vector_type(2)));   // builtin-boundary type
typedef float    v4f  __attribute__((ext_vector_type(4)));

#define CC 128
#define FF 128
#define KC2 32          // channel-pairs per chunk (64 channels)
#define SX 34           // Xs row stride in half2 (32 px + 2 pad; even => 8B-aligned b64 reads)
#define SW 128          // Ws row stride in half2

struct alignas(16) H2x4 { v2h h[4]; };
struct alignas(8)  H2x2 { v2h h[2]; };

static __device__ __forceinline__ v2h pack2(float a, float b) {
    return __builtin_bit_cast(v2h, __builtin_amdgcn_cvt_pkrtz(a, b));
}

__global__ __launch_bounds__(256, 4)
void adder2d_kernel(const float* __restrict__ x,
                    const float* __restrict__ kern,
                    const float* __restrict__ bias,
                    float* __restrict__ out)
{
    __shared__ v2h Xs[KC2 * SX];    //  4.3 KB: [kk2][px]  half2 = (x[c],x[c+1]) per pixel
    __shared__ v2h Wsm[KC2 * SW];   // 16.4 KB: [kk2][f]   half2 = (w[c][f],w[c+1][f])

    const int t  = threadIdx.x;
    const int r  = blockIdx.x;      // 0..1023 = global row id
    const int n  = r >> 5;          // image
    const int h  = r & 31;          // row within image

    // compute mapping: 16 pixel-groups (2 px) x 16 filter-groups (8 f)
    const int pg = t >> 4;
    const int fg = t & 15;
    const int f0 = fg << 3;
    const int p0 = pg << 1;

    float acc[2][8];
#pragma unroll
    for (int pi = 0; pi < 2; ++pi)
#pragma unroll
        for (int fi = 0; fi < 8; ++fi) acc[pi][fi] = 0.f;

    // X staging mapping: thread loads 8 consecutive channels of one pixel
    const int sp = t >> 3;          // pixel 0..31
    const int sa = t & 7;           // channel-octet 0..7 (coalesced)

    for (int ij = 0; ij < 9; ++ij) {
        const int di = ij / 3 - 1;
        const int dj = ij % 3 - 1;
        const int hh = h + di;
        const bool rowok = ((unsigned)hh) < 32u;
        const int  wx = sp + dj;
        const bool xok = rowok && (((unsigned)wx) < 32u);
        const float* xsrc = x + (((n * 32 + hh) * 32 + wx) * CC) + (sa << 3);

        for (int cs = 0; cs < 2; ++cs) {
            const int c0 = cs << 6;
            __syncthreads();   // protect LDS from previous chunk's readers

            // ---- stage X: 32 px x 64 ch; zeros for OOB => contributes |0-w| like
            // the reference's zero padding ----
            {
                v4f g0 = {0.f, 0.f, 0.f, 0.f}, g1 = {0.f, 0.f, 0.f, 0.f};
                if (xok) {
                    const float* s = xsrc + c0;
                    g0 = *(const v4f*)s;
                    g1 = *(const v4f*)(s + 4);
                }
                const int kb = sa << 2;
                Xs[(kb + 0) * SX + sp] = pack2(g0.x, g0.y);
                Xs[(kb + 1) * SX + sp] = pack2(g0.z, g0.w);
                Xs[(kb + 2) * SX + sp] = pack2(g1.x, g1.y);
                Xs[(kb + 3) * SX + sp] = pack2(g1.z, g1.w);
            }

            // ---- stage W: 32 kk2 x 128 f (global layout is f-contiguous: coalesced) ----
#pragma unroll
            for (int pass = 0; pass < 4; ++pass) {
                const int idx = (pass << 8) + t;
                const int kk2 = idx >> 5;          // 0..31
                const int f4  = (idx & 31) << 2;   // 0..124
                const float* s = kern + ((ij * CC + c0 + (kk2 << 1)) * FF) + f4;
                v4f ga = *(const v4f*)s;           // channel c
                v4f gb = *(const v4f*)(s + FF);    // channel c+1
                H2x4 wq;
                wq.h[0] = pack2(ga.x, gb.x);
                wq.h[1] = pack2(ga.y, gb.y);
                wq.h[2] = pack2(ga.z, gb.z);
                wq.h[3] = pack2(ga.w, gb.w);
                *(H2x4*)&Wsm[kk2 * SW + f4] = wq;
            }
            __syncthreads();

            // ---- compute: per kk2: 3 LDS reads + 16 outputs * 3 VALU ----
#pragma unroll 8
            for (int kk2 = 0; kk2 < KC2; ++kk2) {
                const H2x2 xv = *(const H2x2*)&Xs[kk2 * SX + p0];
                const H2x4 wa = *(const H2x4*)&Wsm[kk2 * SW + f0];
                const H2x4 wb = *(const H2x4*)&Wsm[kk2 * SW + f0 + 4];
#pragma unroll
                for (int pi = 0; pi < 2; ++pi) {
                    const v2h xp = xv.h[pi];
#pragma unroll
                    for (int fi = 0; fi < 8; ++fi) {
                        const v2h wv = (fi < 4) ? wa.h[fi] : wb.h[fi - 4];
                        v2h d = xp - wv;                                   // v_pk_add_f16
                        unsigned ad = __builtin_bit_cast(unsigned, d) & 0x7FFF7FFFu; // packed abs
#if __has_builtin(__builtin_amdgcn_fdot2)
                        const v2hb av = __builtin_bit_cast(v2hb, ad);
                        const v2hb ones = {(__fp16)1.0f, (__fp16)1.0f};
                        acc[pi][fi] = __builtin_amdgcn_fdot2(av, ones, acc[pi][fi], false);
#else
                        const v2h av = __builtin_bit_cast(v2h, ad);
                        acc[pi][fi] += (float)av.x + (float)av.y;
#endif
                    }
                }
            }
        }
    }

    // ---- epilogue: out = bias - acc ----
    const v4f b0 = *(const v4f*)(bias + f0);
    const v4f b1 = *(const v4f*)(bias + f0 + 4);
#pragma unroll
    for (int pi = 0; pi < 2; ++pi) {
        float* dst = out + ((r * 32 + p0 + pi) * FF) + f0;
        v4f o0, o1;
        o0.x = b0.x - acc[pi][0];
        o0.y = b0.y - acc[pi][1];
        o0.z = b0.z - acc[pi][2];
        o0.w = b0.w - acc[pi][3];
        o1.x = b1.x - acc[pi][4];
        o1.y = b1.y - acc[pi][5];
        o1.z = b1.z - acc[pi][6];
        o1.w = b1.w - acc[pi][7];
        *(v4f*)dst = o0;
        *(v4f*)(dst + 4) = o1;
    }
}

extern "C" void kernel_launch(void* const* d_in, const int* in_sizes, int n_in,
                              void* d_out, int out_size, void* d_ws, size_t ws_size,
                              hipStream_t stream) {
    const float* x    = (const float*)d_in[0];
    const float* kern = (const float*)d_in[1];
    const float* bias = (const float*)d_in[2];
    float* out = (float*)d_out;
    dim3 grid(1024);   // 32 images * 32 rows
    dim3 block(256);
    adder2d_kernel<<<grid, block, 0, stream>>>(x, kern, bias, out);
}